// Round 2
// baseline (678.072 us; speedup 1.0000x reference)
//
#include <hip/hip_runtime.h>
#include <math.h>

#define B  8
#define T  16
#define C  64
#define H  56
#define W  56
#define HW (H*W)          // 3136
#define HW4 (HW/4)        // 784
#define DS 8
#define DIN (DS*DS)       // 64
#define DOUT 32
#define BC (B*C)          // 512

// ---------------------------------------------------------------------------
// Kernel 1: adaptive avg pool 56x56 -> 8x8 per (b,t,c) slice.
// One wave per slice; all 64 lanes stage + all 64 lanes reduce (one output each).
// pooled layout: [b*C+c][t][64]
// ---------------------------------------------------------------------------
__global__ __launch_bounds__(64) void pool_kernel(const float* __restrict__ x,
                                                  float* __restrict__ pooled) {
    __shared__ float lds[HW];
    const int bid = blockIdx.x;           // [0, B*T*C)
    const int tid = threadIdx.x;
    const int b = bid >> 10;              // / (T*C)
    const int t = (bid >> 6) & (T - 1);
    const int c = bid & (C - 1);

    const float4* x4 = (const float4*)x + (size_t)bid * HW4;
    float4* l4 = (float4*)lds;
    for (int i = tid; i < HW4; i += 64) l4[i] = x4[i];
    __syncthreads();

    const int i = tid >> 3;               // pooled row
    const int j = tid & 7;                // pooled col
    float s = 0.f;
    const int base = (7 * i) * W + 7 * j;
    #pragma unroll
    for (int di = 0; di < 7; ++di) {
        #pragma unroll
        for (int dj = 0; dj < 7; ++dj) s += lds[base + di * W + dj];
    }
    pooled[(((b * C + c) * T) + t) * DIN + tid] = s * (1.0f / 49.0f);
}

// ---------------------------------------------------------------------------
// Kernel 2: per n in [0,512): q = flat@Wq+bq, k = flat@Wk+bk,
// att = softmax(q k^T / 4). Writes att [512][16][16].
// ---------------------------------------------------------------------------
__global__ __launch_bounds__(256) void att_kernel(const float* __restrict__ pooled,
                                                  const float* __restrict__ Wq,
                                                  const float* __restrict__ bq,
                                                  const float* __restrict__ Wk,
                                                  const float* __restrict__ bk,
                                                  float* __restrict__ att_g) {
    __shared__ float flat_s[T * DIN];     // 1024
    __shared__ float wq_s[DIN * DOUT];    // 2048
    __shared__ float wk_s[DIN * DOUT];    // 2048
    __shared__ float qs[T * DOUT];        // 512
    __shared__ float ks[T * DOUT];        // 512
    __shared__ float att_s[T * T];        // 256

    const int n = blockIdx.x;
    const int tid = threadIdx.x;

    for (int e = tid; e < T * DIN; e += 256) flat_s[e] = pooled[n * (T * DIN) + e];
    for (int e = tid; e < DIN * DOUT; e += 256) { wq_s[e] = Wq[e]; wk_s[e] = Wk[e]; }
    __syncthreads();

    for (int e = tid; e < T * DOUT; e += 256) {
        const int t = e >> 5;
        const int d = e & 31;
        float sq = bq[d];
        float sk = bk[d];
        #pragma unroll
        for (int kk = 0; kk < DIN; ++kk) {
            const float f = flat_s[t * DIN + kk];
            sq = fmaf(f, wq_s[kk * DOUT + d], sq);
            sk = fmaf(f, wk_s[kk * DOUT + d], sk);
        }
        qs[e] = sq;
        ks[e] = sk;
    }
    __syncthreads();

    {
        const int tt = tid >> 4;
        const int ss = tid & 15;
        float s = 0.f;
        #pragma unroll
        for (int d = 0; d < DOUT; ++d) s = fmaf(qs[tt * DOUT + d], ks[ss * DOUT + d], s);
        att_s[tid] = s * 0.25f;           // 1/sqrt(16)
    }
    __syncthreads();

    if (tid < T) {
        const int r = tid;
        float m = -INFINITY;
        #pragma unroll
        for (int s = 0; s < T; ++s) m = fmaxf(m, att_s[r * T + s]);
        float e[T];
        float sum = 0.f;
        #pragma unroll
        for (int s = 0; s < T; ++s) { e[s] = __expf(att_s[r * T + s] - m); sum += e[s]; }
        const float inv = 1.0f / sum;
        #pragma unroll
        for (int s = 0; s < T; ++s) att_g[n * (T * T) + r * T + s] = e[s] * inv;
    }
}

// ---------------------------------------------------------------------------
// Kernel 3: out[b,t,c,p] = sum_s att[b*C+c][t][s] * x[b,s,c,p]
// Block = 4 waves. Waves split the t-dim (waves 0,1 -> t 0..7; waves 2,3 ->
// t 8..15) and pair up on interleaved 64-pixel groups, so each x float4 is
// loaded by 2 waves on the same CU (L1 hit for the duplicate). acc[8] float4
// = 32 VGPRs per thread -> no spills, 4 waves/SIMD occupancy.
// ---------------------------------------------------------------------------
__global__ __launch_bounds__(256, 4) void apply_kernel(const float* __restrict__ x,
                                                       const float* __restrict__ att_g,
                                                       float* __restrict__ out) {
    __shared__ float att_s[T * T];
    const int n = blockIdx.x;             // [0,512) = b*C+c
    const int half = blockIdx.y;          // [0,2)
    const int tid = threadIdx.x;
    const int lane = tid & 63;
    const int wave = tid >> 6;            // 0..3
    const int thalf = wave >> 1;          // 0..1 : which 8 t-values
    const int pgrp = wave & 1;            // 0..1 : which 64-pixel group
    const int b = n >> 6;
    const int c = n & 63;

    att_s[tid] = att_g[n * (T * T) + (tid & (T * T - 1))];  // 256 thr, 256 elems
    __syncthreads();

    const float4* x4 = (const float4*)x;
    float4* o4 = (float4*)out;
    const int p_begin = half * (HW4 / 2);         // 0 or 392
    const int p_end = p_begin + (HW4 / 2);

    for (int p4 = p_begin + pgrp * 64 + lane; p4 < p_end; p4 += 128) {
        float4 acc[8];
        #pragma unroll
        for (int t = 0; t < 8; ++t) acc[t] = make_float4(0.f, 0.f, 0.f, 0.f);

        #pragma unroll
        for (int s = 0; s < T; ++s) {
            const float4 xv = x4[((size_t)(b * T + s) * C + c) * HW4 + p4];
            #pragma unroll
            for (int t = 0; t < 8; ++t) {
                const float a = att_s[(thalf * 8 + t) * T + s];  // wave-uniform broadcast
                acc[t].x = fmaf(a, xv.x, acc[t].x);
                acc[t].y = fmaf(a, xv.y, acc[t].y);
                acc[t].z = fmaf(a, xv.z, acc[t].z);
                acc[t].w = fmaf(a, xv.w, acc[t].w);
            }
        }
        #pragma unroll
        for (int t = 0; t < 8; ++t)
            o4[((size_t)(b * T + thalf * 8 + t) * C + c) * HW4 + p4] = acc[t];
    }
}

extern "C" void kernel_launch(void* const* d_in, const int* in_sizes, int n_in,
                              void* d_out, int out_size, void* d_ws, size_t ws_size,
                              hipStream_t stream) {
    const float* x  = (const float*)d_in[0];
    const float* Wq = (const float*)d_in[1];
    const float* bq = (const float*)d_in[2];
    const float* Wk = (const float*)d_in[3];
    const float* bk = (const float*)d_in[4];
    float* out = (float*)d_out;

    float* pooled = (float*)d_ws;                         // 512*16*64 floats
    float* att_g  = pooled + (size_t)BC * T * DIN;        // 512*256 floats

    pool_kernel<<<dim3(B * T * C), dim3(64), 0, stream>>>(x, pooled);
    att_kernel<<<dim3(BC), dim3(256), 0, stream>>>(pooled, Wq, bq, Wk, bk, att_g);
    apply_kernel<<<dim3(BC, 2), dim3(256), 0, stream>>>(x, att_g, out);
}

// Round 3
// 219.155 us; speedup vs baseline: 3.0940x; 3.0940x over previous
//
#include <hip/hip_runtime.h>
#include <math.h>

#define B  8
#define T  16
#define C  64
#define H  56
#define W  56
#define HW (H*W)          // 3136
#define HW2 (HW/2)        // 1568
#define HW4 (HW/4)        // 784
#define DS 8
#define DIN (DS*DS)       // 64
#define DOUT 32
#define BC (B*C)          // 512

// ---------------------------------------------------------------------------
// Kernel 1: adaptive avg pool 56x56 -> 8x8 per (b,t,c) slice.
// One wave per slice; 64 lanes stage via float4, 64 lanes reduce (one 7x7
// window each). pooled layout: [b*C+c][t][64]
// ---------------------------------------------------------------------------
__global__ __launch_bounds__(64) void pool_kernel(const float* __restrict__ x,
                                                  float* __restrict__ pooled) {
    __shared__ float lds[HW];
    const int bid = blockIdx.x;           // [0, B*T*C)
    const int tid = threadIdx.x;
    const int b = bid >> 10;
    const int t = (bid >> 6) & (T - 1);
    const int c = bid & (C - 1);

    const float4* x4 = (const float4*)x + (size_t)bid * HW4;
    float4* l4 = (float4*)lds;
    for (int i = tid; i < HW4; i += 64) l4[i] = x4[i];
    __syncthreads();

    const int i = tid >> 3;
    const int j = tid & 7;
    float s = 0.f;
    const int base = (7 * i) * W + 7 * j;
    #pragma unroll
    for (int di = 0; di < 7; ++di) {
        #pragma unroll
        for (int dj = 0; dj < 7; ++dj) s += lds[base + di * W + dj];
    }
    pooled[(((b * C + c) * T) + t) * DIN + tid] = s * (1.0f / 49.0f);
}

// ---------------------------------------------------------------------------
// Kernel 2: per n: q = flat@Wq+bq, k = flat@Wk+bk, att = softmax(q k^T / 4).
// Writes att [512][16][16].
// ---------------------------------------------------------------------------
__global__ __launch_bounds__(256) void att_kernel(const float* __restrict__ pooled,
                                                  const float* __restrict__ Wq,
                                                  const float* __restrict__ bq,
                                                  const float* __restrict__ Wk,
                                                  const float* __restrict__ bk,
                                                  float* __restrict__ att_g) {
    __shared__ float flat_s[T * DIN];
    __shared__ float wq_s[DIN * DOUT];
    __shared__ float wk_s[DIN * DOUT];
    __shared__ float qs[T * DOUT];
    __shared__ float ks[T * DOUT];
    __shared__ float att_s[T * T];

    const int n = blockIdx.x;
    const int tid = threadIdx.x;

    for (int e = tid; e < T * DIN; e += 256) flat_s[e] = pooled[n * (T * DIN) + e];
    for (int e = tid; e < DIN * DOUT; e += 256) { wq_s[e] = Wq[e]; wk_s[e] = Wk[e]; }
    __syncthreads();

    for (int e = tid; e < T * DOUT; e += 256) {
        const int t = e >> 5;
        const int d = e & 31;
        float sq = bq[d];
        float sk = bk[d];
        #pragma unroll
        for (int kk = 0; kk < DIN; ++kk) {
            const float f = flat_s[t * DIN + kk];
            sq = fmaf(f, wq_s[kk * DOUT + d], sq);
            sk = fmaf(f, wk_s[kk * DOUT + d], sk);
        }
        qs[e] = sq;
        ks[e] = sk;
    }
    __syncthreads();

    {
        const int tt = tid >> 4;
        const int ss = tid & 15;
        float s = 0.f;
        #pragma unroll
        for (int d = 0; d < DOUT; ++d) s = fmaf(qs[tt * DOUT + d], ks[ss * DOUT + d], s);
        att_s[tid] = s * 0.25f;
    }
    __syncthreads();

    if (tid < T) {
        const int r = tid;
        float m = -INFINITY;
        #pragma unroll
        for (int s = 0; s < T; ++s) m = fmaxf(m, att_s[r * T + s]);
        float e[T];
        float sum = 0.f;
        #pragma unroll
        for (int s = 0; s < T; ++s) { e[s] = __expf(att_s[r * T + s] - m); sum += e[s]; }
        const float inv = 1.0f / sum;
        #pragma unroll
        for (int s = 0; s < T; ++s) att_g[n * (T * T) + r * T + s] = e[s] * inv;
    }
}

// ---------------------------------------------------------------------------
// Kernel 3: out[b,t,c,p] = sum_s att[b*C+c][t][s] * x[b,s,c,p]
// Grid (512, 8): block handles n and a 196-float2 pixel chunk. Each thread
// owns ONE float2 column (no outer loop -> nothing to software-pipeline into
// extra live registers). acc[16] float2 = 32 VGPRs. att transposed in LDS so
// the 16 att values for one s are contiguous (ds_read_b128-mergeable).
// Non-temporal stores keep x resident in L3 for the fetch side.
// ---------------------------------------------------------------------------
#define PCHUNK (HW2 / 8)   // 196 float2 per block
__global__ __launch_bounds__(256) void apply_kernel(const float* __restrict__ x,
                                                    const float* __restrict__ att_g,
                                                    float* __restrict__ out) {
    __shared__ float attT[T * T];         // attT[s][t]
    const int n = blockIdx.x;             // [0,512) = b*C+c
    const int chunk = blockIdx.y;         // [0,8)
    const int tid = threadIdx.x;
    const int b = n >> 6;
    const int c = n & 63;

    {   // load att row-major [t][s], store transposed [s][t]
        const int t = tid >> 4;
        const int s = tid & 15;
        attT[s * T + t] = att_g[n * (T * T) + tid];
    }
    __syncthreads();

    if (tid >= PCHUNK) return;
    const int p = chunk * PCHUNK + tid;   // float2 column index in [0, 1568)

    const float2* x2 = (const float2*)x;
    float2* o2 = (float2*)out;

    float2 acc[T];
    #pragma unroll
    for (int t = 0; t < T; ++t) acc[t] = make_float2(0.f, 0.f);

    #pragma unroll 4
    for (int s = 0; s < T; ++s) {
        const float2 xv = x2[((size_t)(b * T + s) * C + c) * HW2 + p];
        #pragma unroll
        for (int t = 0; t < T; ++t) {
            const float a = attT[s * T + t];
            acc[t].x = fmaf(a, xv.x, acc[t].x);
            acc[t].y = fmaf(a, xv.y, acc[t].y);
        }
    }

    #pragma unroll
    for (int t = 0; t < T; ++t) {
        double* dst = (double*)&o2[((size_t)(b * T + t) * C + c) * HW2 + p];
        __builtin_nontemporal_store(*(const double*)&acc[t], dst);
    }
}

extern "C" void kernel_launch(void* const* d_in, const int* in_sizes, int n_in,
                              void* d_out, int out_size, void* d_ws, size_t ws_size,
                              hipStream_t stream) {
    const float* x  = (const float*)d_in[0];
    const float* Wq = (const float*)d_in[1];
    const float* bq = (const float*)d_in[2];
    const float* Wk = (const float*)d_in[3];
    const float* bk = (const float*)d_in[4];
    float* out = (float*)d_out;

    float* pooled = (float*)d_ws;                         // 512*16*64 floats
    float* att_g  = pooled + (size_t)BC * T * DIN;        // 512*256 floats

    pool_kernel<<<dim3(B * T * C), dim3(64), 0, stream>>>(x, pooled);
    att_kernel<<<dim3(BC), dim3(256), 0, stream>>>(pooled, Wq, bq, Wk, bk, att_g);
    apply_kernel<<<dim3(BC, 8), dim3(256), 0, stream>>>(x, att_g, out);
}

// Round 4
// 218.275 us; speedup vs baseline: 3.1065x; 1.0040x over previous
//
#include <hip/hip_runtime.h>
#include <math.h>

#define B  8
#define T  16
#define C  64
#define H  56
#define W  56
#define HW (H*W)          // 3136
#define HW4 (HW/4)        // 784
#define DS 8
#define DIN (DS*DS)       // 64
#define DOUT 32
#define BC (B*C)          // 512

typedef float vfloat4 __attribute__((ext_vector_type(4)));

// ---------------------------------------------------------------------------
// Fused pool + q/k + softmax. One block per n = b*C+c (512 blocks, 256 thr).
// Phase A: stage 4 t-slices (50 KB LDS) at a time, each thread reduces one
//          7x7 window (2-way bank pattern = free).
// Phase B: q/k (64->32 linear), 16x16 logits, softmax -> att_g[n][16][16].
// LDS total ~74 KB -> 2 blocks/CU, all 512 resident.
// ---------------------------------------------------------------------------
__global__ __launch_bounds__(256) void pool_att_kernel(const float* __restrict__ x,
                                                       const float* __restrict__ Wq,
                                                       const float* __restrict__ bq,
                                                       const float* __restrict__ Wk,
                                                       const float* __restrict__ bk,
                                                       float* __restrict__ att_g) {
    __shared__ float xs[4 * HW];          // 50176 B
    __shared__ float pooled_s[T * DIN];   // 4 KB
    __shared__ float wq_s[DIN * DOUT];    // 8 KB
    __shared__ float wk_s[DIN * DOUT];    // 8 KB
    __shared__ float qs[T * DOUT];        // 2 KB
    __shared__ float ks[T * 33];          // padded stride 33 (kills 16-way conflict)
    __shared__ float att_s[T * T];        // 1 KB

    const int n = blockIdx.x;             // b*C + c
    const int tid = threadIdx.x;
    const int b = n >> 6;
    const int c = n & 63;

    // stage the weight matrices while we pool (reused by q/k phase)
    for (int e = tid; e < DIN * DOUT; e += 256) { wq_s[e] = Wq[e]; wk_s[e] = Wk[e]; }

    const float4* x4 = (const float4*)x;
    float4* xs4 = (float4*)xs;

    // ---- Phase A: pool, 4 t-slices per group ----
    #pragma unroll 1
    for (int g = 0; g < 4; ++g) {
        for (int i = tid; i < 4 * HW4; i += 256) {
            const int ti = i / HW4;       // const divisor -> magic mul
            const int p  = i - ti * HW4;
            xs4[i] = x4[((size_t)(b * T + g * 4 + ti) * C + c) * HW4 + p];
        }
        __syncthreads();
        {
            const int ti  = tid >> 6;     // 0..3
            const int wi  = tid & 63;     // window index = i*8+j
            const int ri  = wi >> 3;
            const int rj  = wi & 7;
            float s = 0.f;
            const int base = ti * HW + (7 * ri) * W + 7 * rj;
            #pragma unroll
            for (int di = 0; di < 7; ++di) {
                #pragma unroll
                for (int dj = 0; dj < 7; ++dj) s += xs[base + di * W + dj];
            }
            pooled_s[(g * 4 + ti) * DIN + wi] = s * (1.0f / 49.0f);
        }
        __syncthreads();
    }

    // ---- Phase B: q,k ----
    for (int e = tid; e < T * DOUT; e += 256) {
        const int t = e >> 5;
        const int d = e & 31;
        float sq = bq[d];
        float sk = bk[d];
        #pragma unroll
        for (int kk = 0; kk < DIN; ++kk) {
            const float f = pooled_s[t * DIN + kk];
            sq = fmaf(f, wq_s[kk * DOUT + d], sq);
            sk = fmaf(f, wk_s[kk * DOUT + d], sk);
        }
        qs[t * DOUT + d] = sq;
        ks[t * 33 + d] = sk;
    }
    __syncthreads();

    // logits (one per thread)
    {
        const int tt = tid >> 4;
        const int ss = tid & 15;
        float s = 0.f;
        #pragma unroll
        for (int d = 0; d < DOUT; ++d) s = fmaf(qs[tt * DOUT + d], ks[ss * 33 + d], s);
        att_s[tid] = s * 0.25f;           // 1/sqrt(16)
    }
    __syncthreads();

    // softmax rows (16 threads)
    if (tid < T) {
        const int r = tid;
        float m = -INFINITY;
        #pragma unroll
        for (int s = 0; s < T; ++s) m = fmaxf(m, att_s[r * T + s]);
        float e[T];
        float sum = 0.f;
        #pragma unroll
        for (int s = 0; s < T; ++s) { e[s] = __expf(att_s[r * T + s] - m); sum += e[s]; }
        const float inv = 1.0f / sum;
        #pragma unroll
        for (int s = 0; s < T; ++s) att_g[n * (T * T) + r * T + s] = e[s] * inv;
    }
}

// ---------------------------------------------------------------------------
// apply: out[b,t,c,p] = sum_s att[n][t][s] * x[b,s,c,p]
// Block = 128 threads (2 waves). Wave 0 -> t 0..7, wave 1 -> t 8..15, so
// acc[8] float4 = 32 VGPRs. Grid (512,4): 196 float4 columns per block,
// column loop NOT unrolled (unroll 1) + s-loop unroll 8 to bound in-flight
// loads -> ~85 VGPR, no spill. x loads duplicated across the wave pair are
// same-CU L1 hits. Non-temporal stores.
// ---------------------------------------------------------------------------
__global__ __launch_bounds__(128) void apply_kernel(const float* __restrict__ x,
                                                    const float* __restrict__ att_g,
                                                    float* __restrict__ out) {
    __shared__ float att_s[T * T];
    const int n = blockIdx.x;             // [0,512)
    const int quarter = blockIdx.y;       // [0,4)
    const int tid = threadIdx.x;
    const int lane = tid & 63;
    const int wave = tid >> 6;            // 0..1 -> t-half
    const int b = n >> 6;
    const int c = n & 63;

    for (int e = tid; e < T * T; e += 128) att_s[e] = att_g[n * (T * T) + e];
    __syncthreads();

    const float4* x4 = (const float4*)x;
    float4* o4 = (float4*)out;

    #pragma unroll 1
    for (int i = lane; i < 196; i += 64) {
        const int p4 = quarter * 196 + i;
        float4 acc[8];
        #pragma unroll
        for (int t = 0; t < 8; ++t) acc[t] = make_float4(0.f, 0.f, 0.f, 0.f);

        #pragma unroll 8
        for (int s = 0; s < T; ++s) {
            const float4 xv = x4[((size_t)(b * T + s) * C + c) * HW4 + p4];
            #pragma unroll
            for (int t = 0; t < 8; ++t) {
                const float a = att_s[(wave * 8 + t) * T + s];  // wave-uniform broadcast
                acc[t].x = fmaf(a, xv.x, acc[t].x);
                acc[t].y = fmaf(a, xv.y, acc[t].y);
                acc[t].z = fmaf(a, xv.z, acc[t].z);
                acc[t].w = fmaf(a, xv.w, acc[t].w);
            }
        }

        #pragma unroll
        for (int t = 0; t < 8; ++t) {
            vfloat4* dst = (vfloat4*)&o4[((size_t)(b * T + wave * 8 + t) * C + c) * HW4 + p4];
            vfloat4 v; v.x = acc[t].x; v.y = acc[t].y; v.z = acc[t].z; v.w = acc[t].w;
            __builtin_nontemporal_store(v, dst);
        }
    }
}

extern "C" void kernel_launch(void* const* d_in, const int* in_sizes, int n_in,
                              void* d_out, int out_size, void* d_ws, size_t ws_size,
                              hipStream_t stream) {
    const float* x  = (const float*)d_in[0];
    const float* Wq = (const float*)d_in[1];
    const float* bq = (const float*)d_in[2];
    const float* Wk = (const float*)d_in[3];
    const float* bk = (const float*)d_in[4];
    float* out = (float*)d_out;

    float* att_g = (float*)d_ws;          // 512*256 floats = 512 KB

    pool_att_kernel<<<dim3(BC), dim3(256), 0, stream>>>(x, Wq, bq, Wk, bk, att_g);
    apply_kernel<<<dim3(BC, 4), dim3(128), 0, stream>>>(x, att_g, out);
}